// Round 4
// baseline (249.096 us; speedup 1.0000x reference)
//
#include <hip/hip_runtime.h>
#include <math.h>
#include <stdint.h>

typedef unsigned short u16;
typedef __attribute__((ext_vector_type(8))) short short8;
typedef __attribute__((ext_vector_type(4))) float f32x4;

// gate scale: 0.125 (attn scale) * log2(e)  -> p = exp2(s * gate)
#define GATE_SCALE 0.18033688011112042f

#if __has_builtin(__builtin_amdgcn_exp2f)
#define FEXP2(x) __builtin_amdgcn_exp2f(x)
#else
#define FEXP2(x) exp2f(x)
#endif

// fp32 -> bf16 round-to-nearest-even
__device__ __forceinline__ u16 f2b(float f) {
    union { float f; unsigned u; } v; v.f = f;
    unsigned r = v.u + 0x7fffu + ((v.u >> 16) & 1u);
    return (u16)(r >> 16);
}
// fp32 -> bf16 round-half-up (2 ops; same 0.5-ulp bound, tiny bias)
__device__ __forceinline__ u16 f2b_hu(float f) {
    union { float f; unsigned u; } v; v.f = f;
    return (u16)((v.u + 0x8000u) >> 16);
}
__device__ __forceinline__ float b2f(u16 u) {
    union { float f; unsigned u; } v; v.u = ((unsigned)u) << 16; return v.f;
}

// async global->LDS, 16B per lane. lds base wave-uniform; HW adds lane*16.
#define GLL16(gsrc, ldsbase) __builtin_amdgcn_global_load_lds(                    \
    (__attribute__((address_space(1))) void*)(uintptr_t)(gsrc),                   \
    (__attribute__((address_space(3))) void*)(uint32_t)(uintptr_t)(ldsbase),      \
    16, 0, 0)

// ---------------------------------------------------------------------------
// K0a: convert x / w_qkv / w_proj to bf16.
// ---------------------------------------------------------------------------
#define NX4  1572864   // 6291456/4
#define NW14 442368
#define NW24 147456
#define NXW4 (NX4 + NW14 + NW24)   // 2162688

__global__ __launch_bounds__(256) void prep_xw(
    const float4* __restrict__ x, const float4* __restrict__ wq,
    const float4* __restrict__ wp,
    ushort4* __restrict__ xb, ushort4* __restrict__ wqb,
    ushort4* __restrict__ wpb)
{
    size_t i = (size_t)blockIdx.x * 256 + threadIdx.x;
    float4 v; ushort4* dst; size_t j;
    if (i < NX4)            { j = i;               v = x[j];  dst = xb;  }
    else if (i < NX4 + NW14){ j = i - NX4;         v = wq[j]; dst = wqb; }
    else                    { j = i - (NX4 + NW14);v = wp[j]; dst = wpb; }
    ushort4 o; o.x = f2b(v.x); o.y = f2b(v.y); o.z = f2b(v.z); o.w = f2b(v.w);
    dst[j] = o;
}

// ---------------------------------------------------------------------------
// K0b: gate = bf16(GATE_SCALE * sigmoid(mask)), permuted into MFMA C-fragment
// order: tile (h,qt,kt), lane (w,l) holds rows 16w+4fq+i, cols nt*16+fr at
// tile*4096 + (w*64+l)*16, inner idx = i*4+nt.
// ---------------------------------------------------------------------------
__global__ __launch_bounds__(256) void prep_gate(
    const float* __restrict__ mask, u16* __restrict__ gp)
{
    const int bid = blockIdx.x;                 // h*256 + qt*16 + kt
    const int h = bid >> 8, qt = (bid >> 4) & 15, kt = bid & 15;
    const int t = threadIdx.x, l = t & 63, w = t >> 6;
    const int fq = l >> 4, fr = l & 15;
    const float* mb = mask + ((size_t)h * 1024 + qt * 64 + 16 * w + 4 * fq) * 1024
                           + kt * 64 + fr;
    union { u16 u[16]; float4 f[2]; } vals;
    #pragma unroll
    for (int i = 0; i < 4; ++i)
        #pragma unroll
        for (int nt = 0; nt < 4; ++nt) {
            float m = mb[(size_t)i * 1024 + nt * 16];
            vals.u[i * 4 + nt] = f2b(GATE_SCALE / (1.f + __expf(-m)));
        }
    float4* dst = (float4*)(gp + (size_t)bid * 4096 + (w * 64 + l) * 16);
    dst[0] = vals.f[0];
    dst[1] = vals.f[1];
}

// ---------------------------------------------------------------------------
// K1: QKV GEMM, bf16 MFMA 16x16x32, 128x128 tile, BK=32, software-pipelined:
// double-buffered LDS, ONE barrier per K-iter, prefetch issued right after
// the barrier so it has the whole compute body to land.
// q/k written (B,H,N,64); V written TRANSPOSED (B,H,64,N).
// ---------------------------------------------------------------------------
__global__ __launch_bounds__(256) void qkv_gemm(
    const u16* __restrict__ xb, const u16* __restrict__ wb,
    u16* __restrict__ qb, u16* __restrict__ kb, u16* __restrict__ vb)
{
    __shared__ u16 As[2][4096];
    __shared__ u16 Bs[2][4096];
    const int t = threadIdx.x, l = t & 63, w = t >> 6;
    const int wm = (w & 1) * 64, wn = (w >> 1) * 64;
    const int m0 = blockIdx.y * 128, c0 = blockIdx.x * 128;

    f32x4 acc[4][4];
    #pragma unroll
    for (int i = 0; i < 4; ++i)
        #pragma unroll
        for (int j = 0; j < 4; ++j) { f32x4 z = {0.f,0.f,0.f,0.f}; acc[i][j] = z; }

    const int srow = l >> 2, sseg = l & 3;
    const int gcol = ((sseg ^ (srow & 3)) << 3);
    const u16* a0 = xb + (size_t)(m0 + w * 16 + srow) * 768 + gcol;
    const u16* a1 = a0 + (size_t)64 * 768;
    const u16* b0p = wb + (size_t)(c0 + w * 16 + srow) * 768 + gcol;
    const u16* b1p = b0p + (size_t)64 * 768;
    const int wofs = w * 512;                     // per-wave LDS group offset

    const int fr = l & 15, fq = l >> 4;
    const int fseg = (fq ^ (fr & 3)) << 3;

    // preload k-chunk 0 into buffer 0
    GLL16(a0, &As[0][wofs]);
    GLL16(a1, &As[0][2048 + wofs]);
    GLL16(b0p, &Bs[0][wofs]);
    GLL16(b1p, &Bs[0][2048 + wofs]);

    for (int kt = 0; kt < 24; ++kt) {
        __syncthreads();                          // drains prev-iter prefetch
        if (kt < 23) {                            // prefetch next chunk
            const int kn = (kt + 1) * 32;
            const int nb = (kt + 1) & 1;
            GLL16(a0 + kn, &As[nb][wofs]);
            GLL16(a1 + kn, &As[nb][2048 + wofs]);
            GLL16(b0p + kn, &Bs[nb][wofs]);
            GLL16(b1p + kn, &Bs[nb][2048 + wofs]);
        }
        const u16* A = As[kt & 1];
        const u16* B = Bs[kt & 1];
        short8 af[4], bf[4];
        #pragma unroll
        for (int mt = 0; mt < 4; ++mt)
            af[mt] = *(const short8*)&A[(wm + mt * 16 + fr) * 32 + fseg];
        #pragma unroll
        for (int nt = 0; nt < 4; ++nt)
            bf[nt] = *(const short8*)&B[(wn + nt * 16 + fr) * 32 + fseg];
        #pragma unroll
        for (int mt = 0; mt < 4; ++mt)
            #pragma unroll
            for (int nt = 0; nt < 4; ++nt)
                acc[mt][nt] = __builtin_amdgcn_mfma_f32_16x16x32_bf16(
                    af[mt], bf[nt], acc[mt][nt], 0, 0, 0);
    }

    // epilogue: C row m = m0+wm+mt*16+fq*4+r ; col c = c0+wn+nt*16+fr
    const int b = m0 >> 10;
    const int n0 = m0 & 1023;
    #pragma unroll
    for (int nt = 0; nt < 4; ++nt) {
        const int c = c0 + wn + nt * 16 + fr;
        const int which = c / 768;
        const int rem = c - which * 768;
        const int h = rem >> 6, d = rem & 63;
        if (which < 2) {
            u16* dst = ((which == 0) ? qb : kb)
                       + ((size_t)(b * 12 + h) * 1024) * 64 + d;
            #pragma unroll
            for (int mt = 0; mt < 4; ++mt)
                #pragma unroll
                for (int r = 0; r < 4; ++r) {
                    const int n = n0 + wm + mt * 16 + fq * 4 + r;
                    dst[(size_t)n * 64] = f2b(acc[mt][nt][r]);
                }
        } else {
            // V transposed: vb[(b,h,d,n)], n contiguous -> pack 4 bf16
            u16* dst = vb + ((size_t)(b * 12 + h) * 64 + d) * 1024
                          + n0 + wm + fq * 4;
            #pragma unroll
            for (int mt = 0; mt < 4; ++mt) {
                ushort4 pk;
                pk.x = f2b(acc[mt][nt][0]); pk.y = f2b(acc[mt][nt][1]);
                pk.z = f2b(acc[mt][nt][2]); pk.w = f2b(acc[mt][nt][3]);
                *(ushort4*)(dst + mt * 16) = pk;
            }
        }
    }
}

// ---------------------------------------------------------------------------
// K2: flash attention, bf16 MFMA, no-max softmax, software-pipelined:
// K/V double-buffered in LDS, ONE barrier per kt, prefetch after barrier;
// gate register-prefetched one iter ahead. LDS 48KB.
// ---------------------------------------------------------------------------
__global__ __launch_bounds__(256) void flash_attn(
    const u16* __restrict__ qb, const u16* __restrict__ kb,
    const u16* __restrict__ vt, const u16* __restrict__ gperm,
    u16* __restrict__ aob)
{
    __shared__ u16 Qs[4096], Ks[2][4096], Vts[2][4096], Ps[4096];
    const int t = threadIdx.x, l = t & 63, w = t >> 6;
    const int bid = blockIdx.x;
    const int h = bid >> 7, qt = (bid >> 3) & 15, b = bid & 7;
    const int q0 = qt * 64;
    const u16* hq = qb + (size_t)(b * 12 + h) * 65536;
    const u16* hk = kb + (size_t)(b * 12 + h) * 65536;
    const u16* hv = vt + (size_t)(b * 12 + h) * 65536;
    const u16* hg = gperm + (size_t)(h * 256 + qt * 16) * 4096 + (w * 64 + l) * 16;

    const int sr = l >> 3, ss = l & 7;
    const int sg = ((ss ^ (sr & 7)) << 3);
    const int j0 = w * 2, j1 = w * 2 + 1;

    // preload Q and kt=0 K/V into buffer 0
    GLL16(hq + (size_t)(q0 + j0 * 8 + sr) * 64 + sg, Qs + j0 * 512);
    GLL16(hq + (size_t)(q0 + j1 * 8 + sr) * 64 + sg, Qs + j1 * 512);
    GLL16(hk + (size_t)(j0 * 8 + sr) * 64 + sg, &Ks[0][j0 * 512]);
    GLL16(hk + (size_t)(j1 * 8 + sr) * 64 + sg, &Ks[0][j1 * 512]);
    GLL16(hv + (size_t)(j0 * 8 + sr) * 1024 + sg, &Vts[0][j0 * 512]);
    GLL16(hv + (size_t)(j1 * 8 + sr) * 1024 + sg, &Vts[0][j1 * 512]);

    // gate prefetch for kt=0
    short8 g0 = *(const short8*)(hg);
    short8 g1 = *(const short8*)(hg + 8);

    float l_part[4] = {0.f, 0.f, 0.f, 0.f};
    f32x4 o[4];
    #pragma unroll
    for (int nt = 0; nt < 4; ++nt) { f32x4 z = {0.f,0.f,0.f,0.f}; o[nt] = z; }

    const int fq = l >> 4, fr = l & 15;
    const int sega = ((fq ^ (fr & 7)) << 3);
    const int segb = (((4 + fq) ^ (fr & 7)) << 3);

    for (int kt = 0; kt < 16; ++kt) {
        __syncthreads();                          // drains prev-iter prefetch
        if (kt < 15) {                            // prefetch next K/V chunk
            const int nb = (kt + 1) & 1;
            const size_t ko = (size_t)(kt + 1) * 64;
            GLL16(hk + (ko + j0 * 8 + sr) * 64 + sg, &Ks[nb][j0 * 512]);
            GLL16(hk + (ko + j1 * 8 + sr) * 64 + sg, &Ks[nb][j1 * 512]);
            GLL16(hv + (size_t)(j0 * 8 + sr) * 1024 + ko + sg, &Vts[nb][j0 * 512]);
            GLL16(hv + (size_t)(j1 * 8 + sr) * 1024 + ko + sg, &Vts[nb][j1 * 512]);
        }
        // gate register prefetch for next iter
        const int ktn = (kt < 15) ? kt + 1 : 15;
        short8 gn0 = *(const short8*)(hg + (size_t)ktn * 4096);
        short8 gn1 = *(const short8*)(hg + (size_t)ktn * 4096 + 8);

        const u16* Kc = Ks[kt & 1];
        const u16* Vc = Vts[kt & 1];

        // S = Q . K^T
        short8 aq0 = *(const short8*)&Qs[(16 * w + fr) * 64 + sega];
        short8 aq1 = *(const short8*)&Qs[(16 * w + fr) * 64 + segb];
        f32x4 sv[4];
        #pragma unroll
        for (int nt = 0; nt < 4; ++nt) {
            short8 k0f = *(const short8*)&Kc[(nt * 16 + fr) * 64 + sega];
            short8 k1f = *(const short8*)&Kc[(nt * 16 + fr) * 64 + segb];
            f32x4 z = {0.f,0.f,0.f,0.f};
            z = __builtin_amdgcn_mfma_f32_16x16x32_bf16(aq0, k0f, z, 0, 0, 0);
            z = __builtin_amdgcn_mfma_f32_16x16x32_bf16(aq1, k1f, z, 0, 0, 0);
            sv[nt] = z;
        }

        // p = exp2(s * gate) ; per-lane row sums; write P to per-wave LDS
        #pragma unroll
        for (int i = 0; i < 4; ++i) {
            const int pr = 4 * fq + i;
            #pragma unroll
            for (int nt = 0; nt < 4; ++nt) {
                const int idx = i * 4 + nt;
                const float g = b2f((u16)(idx < 8 ? g0[idx] : g1[idx - 8]));
                const float p = FEXP2(sv[nt][i] * g);
                l_part[i] += p;
                const int col = nt * 16 + fr;
                Ps[w * 1024 + pr * 64 + (((col >> 3) ^ (pr & 7)) << 3) + (col & 7)]
                    = f2b_hu(p);
            }
        }

        // O += P . V  (per-wave Ps, no barrier)
        short8 ap0 = *(const short8*)&Ps[w * 1024 + fr * 64 + sega];
        short8 ap1 = *(const short8*)&Ps[w * 1024 + fr * 64 + segb];
        #pragma unroll
        for (int nt = 0; nt < 4; ++nt) {
            short8 v0 = *(const short8*)&Vc[(nt * 16 + fr) * 64 + sega];
            short8 v1 = *(const short8*)&Vc[(nt * 16 + fr) * 64 + segb];
            o[nt] = __builtin_amdgcn_mfma_f32_16x16x32_bf16(ap0, v0, o[nt], 0, 0, 0);
            o[nt] = __builtin_amdgcn_mfma_f32_16x16x32_bf16(ap1, v1, o[nt], 0, 0, 0);
        }

        g0 = gn0;
        g1 = gn1;
    }

    // one cross-lane l reduction per block
    float l_i[4];
    #pragma unroll
    for (int i = 0; i < 4; ++i) {
        float s = l_part[i];
        s += __shfl_xor(s, 1, 16);
        s += __shfl_xor(s, 2, 16);
        s += __shfl_xor(s, 4, 16);
        s += __shfl_xor(s, 8, 16);
        l_i[i] = s;
    }

    // epilogue -> aob (B,N,768) bf16
    #pragma unroll
    for (int i = 0; i < 4; ++i) {
        const float inv = 1.f / l_i[i];
        const int n = q0 + 16 * w + 4 * fq + i;
        const size_t rowoff = ((size_t)b * 1024 + n) * 768 + h * 64;
        #pragma unroll
        for (int nt = 0; nt < 4; ++nt)
            aob[rowoff + nt * 16 + fr] = f2b(o[nt][i] * inv);
    }
}

// ---------------------------------------------------------------------------
// K3: output projection, bf16 MFMA, pipelined like K1, fp32 out + bias.
// ---------------------------------------------------------------------------
__global__ __launch_bounds__(256) void proj_gemm(
    const u16* __restrict__ aob, const u16* __restrict__ wb,
    const float* __restrict__ bproj, float* __restrict__ out)
{
    __shared__ u16 As[2][4096];
    __shared__ u16 Bs[2][4096];
    const int t = threadIdx.x, l = t & 63, w = t >> 6;
    const int wm = (w & 1) * 64, wn = (w >> 1) * 64;
    const int m0 = blockIdx.y * 128, c0 = blockIdx.x * 128;

    f32x4 acc[4][4];
    #pragma unroll
    for (int i = 0; i < 4; ++i)
        #pragma unroll
        for (int j = 0; j < 4; ++j) { f32x4 z = {0.f,0.f,0.f,0.f}; acc[i][j] = z; }

    const int srow = l >> 2, sseg = l & 3;
    const int gcol = ((sseg ^ (srow & 3)) << 3);
    const u16* a0 = aob + (size_t)(m0 + w * 16 + srow) * 768 + gcol;
    const u16* a1 = a0 + (size_t)64 * 768;
    const u16* b0p = wb + (size_t)(c0 + w * 16 + srow) * 768 + gcol;
    const u16* b1p = b0p + (size_t)64 * 768;
    const int wofs = w * 512;

    const int fr = l & 15, fq = l >> 4;
    const int fseg = (fq ^ (fr & 3)) << 3;

    GLL16(a0, &As[0][wofs]);
    GLL16(a1, &As[0][2048 + wofs]);
    GLL16(b0p, &Bs[0][wofs]);
    GLL16(b1p, &Bs[0][2048 + wofs]);

    for (int kt = 0; kt < 24; ++kt) {
        __syncthreads();
        if (kt < 23) {
            const int kn = (kt + 1) * 32;
            const int nb = (kt + 1) & 1;
            GLL16(a0 + kn, &As[nb][wofs]);
            GLL16(a1 + kn, &As[nb][2048 + wofs]);
            GLL16(b0p + kn, &Bs[nb][wofs]);
            GLL16(b1p + kn, &Bs[nb][2048 + wofs]);
        }
        const u16* A = As[kt & 1];
        const u16* B = Bs[kt & 1];
        short8 af[4], bf[4];
        #pragma unroll
        for (int mt = 0; mt < 4; ++mt)
            af[mt] = *(const short8*)&A[(wm + mt * 16 + fr) * 32 + fseg];
        #pragma unroll
        for (int nt = 0; nt < 4; ++nt)
            bf[nt] = *(const short8*)&B[(wn + nt * 16 + fr) * 32 + fseg];
        #pragma unroll
        for (int mt = 0; mt < 4; ++mt)
            #pragma unroll
            for (int nt = 0; nt < 4; ++nt)
                acc[mt][nt] = __builtin_amdgcn_mfma_f32_16x16x32_bf16(
                    af[mt], bf[nt], acc[mt][nt], 0, 0, 0);
    }

    #pragma unroll
    for (int nt = 0; nt < 4; ++nt) {
        const int c = c0 + wn + nt * 16 + fr;
        const float bias = bproj[c];
        #pragma unroll
        for (int mt = 0; mt < 4; ++mt)
            #pragma unroll
            for (int r = 0; r < 4; ++r) {
                const int m = m0 + wm + mt * 16 + fq * 4 + r;
                out[(size_t)m * 768 + c] = acc[mt][nt][r] + bias;
            }
    }
}

// ---------------------------------------------------------------------------
extern "C" void kernel_launch(void* const* d_in, const int* in_sizes, int n_in,
                              void* d_out, int out_size, void* d_ws, size_t ws_size,
                              hipStream_t stream)
{
    const float* x     = (const float*)d_in[0];
    const float* wqkv  = (const float*)d_in[1];
    const float* wproj = (const float*)d_in[2];
    const float* bproj = (const float*)d_in[3];
    const float* mask  = (const float*)d_in[4];
    float* out = (float*)d_out;

    char* ws = (char*)d_ws;
    u16* gperm  = (u16*)(ws);               // 25,165,824 B
    u16* xb     = (u16*)(ws + 25165824);    // 12,582,912 B
    u16* wqkvb  = (u16*)(ws + 37748736);    //  3,538,944 B
    u16* wprojb = (u16*)(ws + 41287680);    //  1,179,648 B
    u16* qb     = (u16*)(ws + 42467328);    // 12,582,912 B
    u16* kb     = (u16*)(ws + 55050240);    // 12,582,912 B
    u16* vb     = (u16*)(ws + 67633152);    // 12,582,912 B (transposed: B,H,64,N)
    u16* aob    = (u16*)(ws + 80216064);    // 12,582,912 B  (total 92.8 MB)

    prep_xw<<<NXW4 / 256, 256, 0, stream>>>(
        (const float4*)x, (const float4*)wqkv, (const float4*)wproj,
        (ushort4*)xb, (ushort4*)wqkvb, (ushort4*)wprojb);

    prep_gate<<<3072, 256, 0, stream>>>(mask, gperm);

    qkv_gemm<<<dim3(18, 64), 256, 0, stream>>>(xb, wqkvb, qb, kb, vb);

    flash_attn<<<1536, 256, 0, stream>>>(qb, kb, vb, gperm, aob);

    proj_gemm<<<dim3(6, 64), 256, 0, stream>>>(aob, wprojb, bproj, out);
}